// Round 1
// baseline (53.049 us; speedup 1.0000x reference)
//
#include <hip/hip_runtime.h>
#include <math.h>

// HungarianMatcher cost matrix:
//   C[i,j] = 5*L1(pred_box_i, tgt_box_j) + 2*(pos-neg focal at tgt class j) - 2*GIoU
// Shapes: pred_logits [BN,NC], pred_boxes [BN,4], tgt_ids [NT], tgt_bbox [NT,4]
// BN=16*900=14400, NC=91, NT=960. Output [BN,NT] fp32.

#define ALPHA_F   0.25f
#define COST_CLS  2.0f
#define COST_BBOX 5.0f
#define COST_GIOU 2.0f
#define EPS_F     1e-8f

constexpr int MAX_NT = 1024;   // LDS capacity for targets (NT=960 fits)
constexpr int MAX_NC = 128;    // LDS capacity for class table (NC=91 fits)
constexpr int ROWS_PER_BLOCK = 8;
constexpr int THREADS = 256;

struct Tgt { float cx, cy, w, h, x0, y0, x1, y1, area; int id; }; // 40 B

__global__ __launch_bounds__(THREADS) void matcher_cost_kernel(
    const float* __restrict__ logits,   // [BN, NC]
    const float* __restrict__ boxes,    // [BN, 4] cxcywh
    const int*   __restrict__ tids,     // [NT]
    const float* __restrict__ tboxes,   // [NT, 4] cxcywh
    float*       __restrict__ out,      // [BN, NT]
    int BN, int NC, int NT)
{
    __shared__ Tgt   s_t[MAX_NT];
    __shared__ float s_cls[MAX_NC];

    // ---- stage all targets once per block (derived quantities included) ----
    for (int t = threadIdx.x; t < NT; t += THREADS) {
        float4 b = reinterpret_cast<const float4*>(tboxes)[t];
        Tgt tg;
        tg.cx = b.x; tg.cy = b.y; tg.w = b.z; tg.h = b.w;
        tg.x0 = b.x - 0.5f * b.z;  tg.y0 = b.y - 0.5f * b.w;
        tg.x1 = b.x + 0.5f * b.z;  tg.y1 = b.y + 0.5f * b.w;
        tg.area = (tg.x1 - tg.x0) * (tg.y1 - tg.y0);
        tg.id = tids[t];
        s_t[t] = tg;
    }
    __syncthreads();

    const int row0 = blockIdx.x * ROWS_PER_BLOCK;

    for (int r = 0; r < ROWS_PER_BLOCK; ++r) {
        const int row = row0 + r;
        if (row >= BN) break;   // uniform per block -> no divergent barrier

        // ---- per-row focal class-cost table (91 entries) ----
        if (threadIdx.x < NC) {
            float x = logits[(size_t)row * NC + threadIdx.x];
            float p = 1.0f / (1.0f + expf(-x));
            float om = 1.0f - p;
            float neg = (1.0f - ALPHA_F) * p * p * (-logf(om + EPS_F));
            float pos = ALPHA_F * om * om * (-logf(p + EPS_F));
            s_cls[threadIdx.x] = pos - neg;
        }
        __syncthreads();

        // ---- pred box, uniform across the block ----
        const float4 pb = reinterpret_cast<const float4*>(boxes)[row];
        const float px0 = pb.x - 0.5f * pb.z, py0 = pb.y - 0.5f * pb.w;
        const float px1 = pb.x + 0.5f * pb.z, py1 = pb.y + 0.5f * pb.w;
        const float parea = (px1 - px0) * (py1 - py0);

        float* orow = out + (size_t)row * NT;

        for (int j0 = threadIdx.x * 4; j0 < NT; j0 += THREADS * 4) {
            float res[4];
            const int nk = (NT - j0 >= 4) ? 4 : (NT - j0);
            #pragma unroll
            for (int k = 0; k < 4; ++k) {
                if (k < nk) {
                    const Tgt tg = s_t[j0 + k];
                    // L1 in cxcywh space
                    float l1 = fabsf(pb.x - tg.cx) + fabsf(pb.y - tg.cy)
                             + fabsf(pb.z - tg.w)  + fabsf(pb.w - tg.h);
                    // GIoU
                    float ix0 = fmaxf(px0, tg.x0), iy0 = fmaxf(py0, tg.y0);
                    float ix1 = fminf(px1, tg.x1), iy1 = fminf(py1, tg.y1);
                    float iw = fmaxf(ix1 - ix0, 0.0f), ih = fmaxf(iy1 - iy0, 0.0f);
                    float inter = iw * ih;
                    float uni = parea + tg.area - inter;
                    float iou = inter / uni;
                    float cx0 = fminf(px0, tg.x0), cy0 = fminf(py0, tg.y0);
                    float cx1 = fmaxf(px1, tg.x1), cy1 = fmaxf(py1, tg.y1);
                    float cw = fmaxf(cx1 - cx0, 0.0f), ch = fmaxf(cy1 - cy0, 0.0f);
                    float carea = cw * ch;
                    float giou = iou - (carea - uni) / carea;
                    float ccls = s_cls[tg.id];
                    res[k] = COST_BBOX * l1 + COST_CLS * ccls + COST_GIOU * (-giou);
                }
            }
            if (nk == 4) {
                float4 v = make_float4(res[0], res[1], res[2], res[3]);
                *reinterpret_cast<float4*>(orow + j0) = v;
            } else {
                for (int k = 0; k < nk; ++k) orow[j0 + k] = res[k];
            }
        }
        __syncthreads();   // protect s_cls before next row overwrites it
    }
}

extern "C" void kernel_launch(void* const* d_in, const int* in_sizes, int n_in,
                              void* d_out, int out_size, void* d_ws, size_t ws_size,
                              hipStream_t stream) {
    const float* logits = (const float*)d_in[0];
    const float* boxes  = (const float*)d_in[1];
    const int*   tids   = (const int*)d_in[2];
    const float* tboxes = (const float*)d_in[3];
    float* out = (float*)d_out;

    const int BN = in_sizes[1] / 4;       // 14400
    const int NC = in_sizes[0] / BN;      // 91
    const int NT = in_sizes[2];           // 960

    const int grid = (BN + ROWS_PER_BLOCK - 1) / ROWS_PER_BLOCK;  // 1800
    matcher_cost_kernel<<<grid, THREADS, 0, stream>>>(
        logits, boxes, tids, tboxes, out, BN, NC, NT);
}

// Round 2
// 29.532 us; speedup vs baseline: 1.7963x; 1.7963x over previous
//
#include <hip/hip_runtime.h>
#include <math.h>

// HungarianMatcher cost matrix:
//   C[i,j] = 5*L1(pred_box_i, tgt_box_j) + 2*(pos-neg focal at tgt class j) - 2*GIoU
// Shapes: pred_logits [BN,NC], pred_boxes [BN,4], tgt_ids [NT], tgt_bbox [NT,4]
// BN=16*900=14400, NC=91, NT=960. Output [BN,NT] fp32.

#define ALPHA_F   0.25f
#define COST_CLS  2.0f
#define COST_BBOX 5.0f
#define COST_GIOU 2.0f
#define EPS_F     1e-8f

constexpr int THREADS        = 256;
constexpr int ROWS_PER_BLOCK = 8;
constexpr int KMAX           = 4;    // ceil(NT / THREADS) = ceil(960/256)
constexpr int CLS_STRIDE     = 96;   // 91 rounded up; 96%32==0 so bank = id%32

__global__ __launch_bounds__(THREADS) void matcher_cost_kernel(
    const float* __restrict__ logits,   // [BN, NC]
    const float* __restrict__ boxes,    // [BN, 4] cxcywh
    const int*   __restrict__ tids,     // [NT]
    const float* __restrict__ tboxes,   // [NT, 4] cxcywh
    float*       __restrict__ out,      // [BN, NT]
    int BN, int NC, int NT)
{
    __shared__ float s_cls[ROWS_PER_BLOCK * CLS_STRIDE];   // 3 KB

    const int tid  = threadIdx.x;
    const int row0 = blockIdx.x * ROWS_PER_BLOCK;
    const int nrows = (BN - row0 < ROWS_PER_BLOCK) ? (BN - row0) : ROWS_PER_BLOCK;

    // ---- each thread's 4 targets -> registers (row-invariant) ----
    float tcx[KMAX], tcy[KMAX], tw[KMAX], th[KMAX];
    float tx0[KMAX], ty0[KMAX], tx1[KMAX], ty1[KMAX], tarea[KMAX];
    int   tcl[KMAX];
    #pragma unroll
    for (int k = 0; k < KMAX; ++k) {
        const int j = tid + k * THREADS;
        if (j < NT) {
            float4 b = reinterpret_cast<const float4*>(tboxes)[j];
            tcx[k] = b.x; tcy[k] = b.y; tw[k] = b.z; th[k] = b.w;
            tx0[k] = b.x - 0.5f * b.z;  ty0[k] = b.y - 0.5f * b.w;
            tx1[k] = b.x + 0.5f * b.z;  ty1[k] = b.y + 0.5f * b.w;
            tarea[k] = b.z * b.w;
            tcl[k] = tids[j];
        } else {
            tcx[k]=tcy[k]=tw[k]=th[k]=tx0[k]=ty0[k]=tx1[k]=ty1[k]=tarea[k]=0.f;
            tcl[k] = 0;
        }
    }

    // ---- focal class-cost tables for all 8 rows (one coalesced pass) ----
    for (int t = tid; t < nrows * NC; t += THREADS) {
        const int r = t / NC;
        const int c = t - r * NC;
        const float x  = logits[(size_t)(row0 + r) * NC + c];
        const float p  = 1.0f / (1.0f + expf(-x));
        const float om = 1.0f - p;
        const float neg = (1.0f - ALPHA_F) * p * p   * (-logf(om + EPS_F));
        const float pos = ALPHA_F * om * om          * (-logf(p  + EPS_F));
        s_cls[r * CLS_STRIDE + c] = pos - neg;
    }
    __syncthreads();   // the only barrier in the kernel

    // ---- main loop: 8 rows x 4 targets, LDS = one 4B gather per element ----
    for (int r = 0; r < nrows; ++r) {
        const int row = row0 + r;
        const float4 pb = reinterpret_cast<const float4*>(boxes)[row];
        const float px0 = pb.x - 0.5f * pb.z, py0 = pb.y - 0.5f * pb.w;
        const float px1 = pb.x + 0.5f * pb.z, py1 = pb.y + 0.5f * pb.w;
        const float parea = pb.z * pb.w;
        float* __restrict__ orow = out + (size_t)row * NT;
        const float* __restrict__ crow = s_cls + r * CLS_STRIDE;

        #pragma unroll
        for (int k = 0; k < KMAX; ++k) {
            const int j = tid + k * THREADS;
            if (j < NT) {
                // L1 in cxcywh space
                float l1 = fabsf(pb.x - tcx[k]) + fabsf(pb.y - tcy[k])
                         + fabsf(pb.z - tw[k])  + fabsf(pb.w - th[k]);
                // intersection
                float ix0 = fmaxf(px0, tx0[k]), iy0 = fmaxf(py0, ty0[k]);
                float ix1 = fminf(px1, tx1[k]), iy1 = fminf(py1, ty1[k]);
                float iw = fmaxf(ix1 - ix0, 0.0f), ih = fmaxf(iy1 - iy0, 0.0f);
                float inter = iw * ih;
                float uni = parea + tarea[k] - inter;
                float iou = inter * __builtin_amdgcn_rcpf(uni);
                // smallest enclosing box
                float cx0 = fminf(px0, tx0[k]), cy0 = fminf(py0, ty0[k]);
                float cx1 = fmaxf(px1, tx1[k]), cy1 = fmaxf(py1, ty1[k]);
                float cw = fmaxf(cx1 - cx0, 0.0f), ch = fmaxf(cy1 - cy0, 0.0f);
                float carea = cw * ch;
                float giou = iou - (carea - uni) * __builtin_amdgcn_rcpf(carea);
                // gather focal class cost (4B LDS, ~conflict-free)
                float ccls = crow[tcl[k]];
                orow[j] = COST_BBOX * l1 + COST_CLS * ccls - COST_GIOU * giou;
            }
        }
    }
}

extern "C" void kernel_launch(void* const* d_in, const int* in_sizes, int n_in,
                              void* d_out, int out_size, void* d_ws, size_t ws_size,
                              hipStream_t stream) {
    const float* logits = (const float*)d_in[0];
    const float* boxes  = (const float*)d_in[1];
    const int*   tids   = (const int*)d_in[2];
    const float* tboxes = (const float*)d_in[3];
    float* out = (float*)d_out;

    const int BN = in_sizes[1] / 4;       // 14400
    const int NC = in_sizes[0] / BN;      // 91
    const int NT = in_sizes[2];           // 960

    const int grid = (BN + ROWS_PER_BLOCK - 1) / ROWS_PER_BLOCK;  // 1800
    matcher_cost_kernel<<<grid, THREADS, 0, stream>>>(
        logits, boxes, tids, tboxes, out, BN, NC, NT);
}

// Round 3
// 27.002 us; speedup vs baseline: 1.9647x; 1.0937x over previous
//
#include <hip/hip_runtime.h>
#include <math.h>

// HungarianMatcher cost matrix:
//   C[i,j] = 5*L1(pred_box_i, tgt_box_j) + 2*(pos-neg focal at tgt class j) - 2*GIoU
// Shapes: pred_logits [BN,NC], pred_boxes [BN,4], tgt_ids [NT], tgt_bbox [NT,4]
// BN=16*900=14400, NC=91, NT=960. Output [BN,NT] fp32.

#define ALPHA_F   0.25f
#define COST_CLS  2.0f
#define COST_BBOX 5.0f
#define COST_GIOU 2.0f
#define EPS_F     1e-8f

constexpr int THREADS = 256;
constexpr int ROWS    = 8;

// ---------------------------- specialized kernel ----------------------------
template<int NC, int NT>
__global__ __launch_bounds__(THREADS) void matcher_kernel_s(
    const float* __restrict__ logits,   // [BN, NC]
    const float* __restrict__ boxes,    // [BN, 4] cxcywh
    const int*   __restrict__ tids,     // [NT]
    const float* __restrict__ tboxes,   // [NT, 4] cxcywh
    float*       __restrict__ out)      // [BN, NT]
{
    constexpr int CLS_STRIDE = 96;          // 91 -> 96 (bank = id % 32)
    constexpr int JPT = 4;                  // contiguous targets per thread
    constexpr int NJT = NT / JPT;           // 240 active threads
    __shared__ float s_cls[ROWS * CLS_STRIDE];   // 3 KB

    const int tid  = threadIdx.x;
    const int row0 = blockIdx.x * ROWS;
    const bool active = tid < NJT;

    // ---- this thread's 4 contiguous targets -> registers (row-invariant) ----
    float tcx[JPT], tcy[JPT], tw[JPT], th[JPT];
    float tx0[JPT], ty0[JPT], tx1[JPT], ty1[JPT], tarea[JPT];
    int   tcl[JPT];
    if (active) {
        #pragma unroll
        for (int k = 0; k < JPT; ++k) {
            const int j = tid * JPT + k;
            const float4 b = reinterpret_cast<const float4*>(tboxes)[j];
            tcx[k] = b.x; tcy[k] = b.y; tw[k] = b.z; th[k] = b.w;
            tx0[k] = b.x - 0.5f * b.z;  ty0[k] = b.y - 0.5f * b.w;
            tx1[k] = b.x + 0.5f * b.z;  ty1[k] = b.y + 0.5f * b.w;
            tarea[k] = b.z * b.w;
            tcl[k] = tids[j];
        }
    }

    // ---- all 8 rows' pred boxes (wave-uniform) -> registers ----
    float4 pbv[ROWS];
    #pragma unroll
    for (int r = 0; r < ROWS; ++r)
        pbv[r] = reinterpret_cast<const float4*>(boxes)[row0 + r];

    // ---- focal class tables for all 8 rows (one coalesced pass, 728 elems) ----
    for (int t = tid; t < ROWS * NC; t += THREADS) {
        const int r = t / NC;
        const int c = t - r * NC;
        const float x  = logits[(size_t)(row0 + r) * NC + c];
        const float p  = 1.0f / (1.0f + __expf(-x));
        const float om = 1.0f - p;
        const float neg = (1.0f - ALPHA_F) * p * p * (-__logf(om + EPS_F));
        const float pos = ALPHA_F * om * om        * (-__logf(p  + EPS_F));
        s_cls[r * CLS_STRIDE + c] = pos - neg;
    }
    __syncthreads();   // the only barrier

    if (!active) return;

    float* __restrict__ optr = out + (size_t)row0 * NT + tid * JPT;
    #pragma unroll
    for (int r = 0; r < ROWS; ++r) {
        const float4 pb = pbv[r];
        const float px0 = pb.x - 0.5f * pb.z, py0 = pb.y - 0.5f * pb.w;
        const float px1 = pb.x + 0.5f * pb.z, py1 = pb.y + 0.5f * pb.w;
        const float parea = pb.z * pb.w;
        const float* __restrict__ crow = s_cls + r * CLS_STRIDE;

        float rv[JPT];
        #pragma unroll
        for (int k = 0; k < JPT; ++k) {
            // L1 in cxcywh space
            const float l1 = fabsf(pb.x - tcx[k]) + fabsf(pb.y - tcy[k])
                           + fabsf(pb.z - tw[k])  + fabsf(pb.w - th[k]);
            // intersection
            const float ix0 = fmaxf(px0, tx0[k]), iy0 = fmaxf(py0, ty0[k]);
            const float ix1 = fminf(px1, tx1[k]), iy1 = fminf(py1, ty1[k]);
            const float iw = fmaxf(ix1 - ix0, 0.0f), ih = fmaxf(iy1 - iy0, 0.0f);
            const float inter = iw * ih;
            const float uni = parea + tarea[k] - inter;
            const float iou = inter * __builtin_amdgcn_rcpf(uni);
            // smallest enclosing box (no clamps: max >= min always)
            const float cw = fmaxf(px1, tx1[k]) - fminf(px0, tx0[k]);
            const float ch = fmaxf(py1, ty1[k]) - fminf(py0, ty0[k]);
            const float carea = cw * ch;
            const float giou = iou - (carea - uni) * __builtin_amdgcn_rcpf(carea);
            const float ccls = crow[tcl[k]];
            rv[k] = COST_BBOX * l1 + COST_CLS * ccls - COST_GIOU * giou;
        }
        *reinterpret_cast<float4*>(optr) = make_float4(rv[0], rv[1], rv[2], rv[3]);
        optr += NT;
    }
}

// ----------------------------- generic fallback -----------------------------
__global__ __launch_bounds__(THREADS) void matcher_kernel_g(
    const float* __restrict__ logits, const float* __restrict__ boxes,
    const int* __restrict__ tids, const float* __restrict__ tboxes,
    float* __restrict__ out, int BN, int NC, int NT)
{
    extern __shared__ float s_cls_g[];
    const int tid  = threadIdx.x;
    const int row0 = blockIdx.x * ROWS;
    const int nrows = (BN - row0 < ROWS) ? (BN - row0) : ROWS;

    for (int t = tid; t < nrows * NC; t += THREADS) {
        const int r = t / NC, c = t - r * NC;
        const float x  = logits[(size_t)(row0 + r) * NC + c];
        const float p  = 1.0f / (1.0f + expf(-x));
        const float om = 1.0f - p;
        const float neg = (1.0f - ALPHA_F) * p * p * (-logf(om + EPS_F));
        const float pos = ALPHA_F * om * om        * (-logf(p + EPS_F));
        s_cls_g[r * NC + c] = pos - neg;
    }
    __syncthreads();

    for (int r = 0; r < nrows; ++r) {
        const int row = row0 + r;
        const float4 pb = reinterpret_cast<const float4*>(boxes)[row];
        const float px0 = pb.x - 0.5f * pb.z, py0 = pb.y - 0.5f * pb.w;
        const float px1 = pb.x + 0.5f * pb.z, py1 = pb.y + 0.5f * pb.w;
        const float parea = pb.z * pb.w;
        for (int j = tid; j < NT; j += THREADS) {
            const float4 b = reinterpret_cast<const float4*>(tboxes)[j];
            const float bx0 = b.x - 0.5f * b.z, by0 = b.y - 0.5f * b.w;
            const float bx1 = b.x + 0.5f * b.z, by1 = b.y + 0.5f * b.w;
            const float l1 = fabsf(pb.x - b.x) + fabsf(pb.y - b.y)
                           + fabsf(pb.z - b.z) + fabsf(pb.w - b.w);
            const float iw = fmaxf(fminf(px1, bx1) - fmaxf(px0, bx0), 0.0f);
            const float ih = fmaxf(fminf(py1, by1) - fmaxf(py0, by0), 0.0f);
            const float inter = iw * ih;
            const float uni = parea + b.z * b.w - inter;
            const float iou = inter / uni;
            const float cw = fmaxf(px1, bx1) - fminf(px0, bx0);
            const float ch = fmaxf(py1, by1) - fminf(py0, by0);
            const float carea = cw * ch;
            const float giou = iou - (carea - uni) / carea;
            const float ccls = s_cls_g[r * NC + tids[j]];
            out[(size_t)row * NT + j] = COST_BBOX * l1 + COST_CLS * ccls - COST_GIOU * giou;
        }
        __syncthreads();
    }
}

extern "C" void kernel_launch(void* const* d_in, const int* in_sizes, int n_in,
                              void* d_out, int out_size, void* d_ws, size_t ws_size,
                              hipStream_t stream) {
    const float* logits = (const float*)d_in[0];
    const float* boxes  = (const float*)d_in[1];
    const int*   tids   = (const int*)d_in[2];
    const float* tboxes = (const float*)d_in[3];
    float* out = (float*)d_out;

    const int BN = in_sizes[1] / 4;       // 14400
    const int NC = in_sizes[0] / BN;      // 91
    const int NT = in_sizes[2];           // 960

    if (NC == 91 && NT == 960 && BN % ROWS == 0) {
        const int grid = BN / ROWS;       // 1800
        matcher_kernel_s<91, 960><<<grid, THREADS, 0, stream>>>(
            logits, boxes, tids, tboxes, out);
    } else {
        const int grid = (BN + ROWS - 1) / ROWS;
        const size_t shmem = (size_t)ROWS * NC * sizeof(float);
        matcher_kernel_g<<<grid, THREADS, shmem, stream>>>(
            logits, boxes, tids, tboxes, out, BN, NC, NT);
    }
}

// Round 4
// 24.612 us; speedup vs baseline: 2.1554x; 1.0971x over previous
//
#include <hip/hip_runtime.h>
#include <math.h>

// HungarianMatcher cost matrix:
//   C[i,j] = 5*L1(pred_box_i, tgt_box_j) + 2*(pos-neg focal at tgt class j) - 2*GIoU
// Shapes: pred_logits [BN,NC], pred_boxes [BN,4], tgt_ids [NT], tgt_bbox [NT,4]
// BN=16*900=14400, NC=91, NT=960. Output [BN,NT] fp32.

#define ALPHA_F   0.25f
#define COST_CLS  2.0f
#define COST_BBOX 5.0f
#define COST_GIOU 2.0f
#define EPS_F     1e-8f

constexpr int THREADS = 256;
constexpr int ROWS    = 8;

// ---------------------------- specialized kernel ----------------------------
template<int NC, int NT>
__global__ __launch_bounds__(THREADS) void matcher_kernel_s(
    const float* __restrict__ logits,   // [BN, NC]
    const float* __restrict__ boxes,    // [BN, 4] cxcywh
    const int*   __restrict__ tids,     // [NT]
    const float* __restrict__ tboxes,   // [NT, 4] cxcywh
    float*       __restrict__ out)      // [BN, NT]
{
    constexpr int CLS_STRIDE = 96;           // 91 -> 96
    constexpr int JPT = 4;                   // contiguous targets per thread
    constexpr int NJT = NT / JPT;            // 240 active threads
    constexpr int NTAB = ROWS * NC;          // 728 table entries
    constexpr int LPT  = (NTAB + THREADS - 1) / THREADS;  // 3 logits per thread
    __shared__ float s_cls[ROWS * CLS_STRIDE];            // 3 KB

    const int tid  = threadIdx.x;
    const int row0 = blockIdx.x * ROWS;
    const bool active = tid < NJT;

    // ---- issue logits loads first (longest dependent chain: exp/log table) ----
    const float* __restrict__ lg = logits + (size_t)row0 * NC;  // contiguous 728
    float lv[LPT];
    #pragma unroll
    for (int i = 0; i < LPT; ++i) {
        const int t = tid + i * THREADS;
        lv[i] = (t < NTAB) ? lg[t] : 0.0f;
    }

    // ---- this thread's 4 contiguous targets: raw cxcywh + ids (20 VGPR) ----
    float4 tb[JPT];
    int4 tv = make_int4(0, 0, 0, 0);
    if (active) {
        #pragma unroll
        for (int k = 0; k < JPT; ++k)
            tb[k] = reinterpret_cast<const float4*>(tboxes)[tid * JPT + k];
        tv = reinterpret_cast<const int4*>(tids)[tid];
    }
    const int icl[JPT] = {tv.x, tv.y, tv.z, tv.w};

    // ---- focal class tables for all 8 rows ----
    #pragma unroll
    for (int i = 0; i < LPT; ++i) {
        const int t = tid + i * THREADS;
        if (t < NTAB) {
            const float p  = 1.0f / (1.0f + __expf(-lv[i]));
            const float om = 1.0f - p;
            const float neg = (1.0f - ALPHA_F) * p * p * (-__logf(om + EPS_F));
            const float pos = ALPHA_F * om * om        * (-__logf(p  + EPS_F));
            const int r = t / NC, c = t - r * NC;
            s_cls[r * CLS_STRIDE + c] = pos - neg;
        }
    }
    __syncthreads();   // the only barrier

    if (!active) return;

    float* __restrict__ optr = out + (size_t)row0 * NT + tid * JPT;
    #pragma unroll
    for (int r = 0; r < ROWS; ++r) {
        // block-uniform pred box: scalar-load path, no VGPR cache needed
        const float4 pb = reinterpret_cast<const float4*>(boxes)[row0 + r];
        const float px0 = pb.x - 0.5f * pb.z, py0 = pb.y - 0.5f * pb.w;
        const float px1 = pb.x + 0.5f * pb.z, py1 = pb.y + 0.5f * pb.w;
        const float parea = pb.z * pb.w;
        const float* __restrict__ crow = s_cls + r * CLS_STRIDE;

        float rv[JPT];
        #pragma unroll
        for (int k = 0; k < JPT; ++k) {
            const float4 t = tb[k];
            // derive target xyxy + area on the fly
            const float hw = 0.5f * t.z, hh = 0.5f * t.w;
            const float tx0 = t.x - hw, tx1 = t.x + hw;
            const float ty0 = t.y - hh, ty1 = t.y + hh;
            const float tarea = t.z * t.w;
            // L1 in cxcywh space
            const float l1 = (fabsf(pb.x - t.x) + fabsf(pb.y - t.y))
                           + (fabsf(pb.z - t.z) + fabsf(pb.w - t.w));
            // raw intersection extents (also feed the enclosing box)
            const float iwr = fminf(px1, tx1) - fmaxf(px0, tx0);
            const float ihr = fminf(py1, ty1) - fmaxf(py0, ty0);
            const float inter = fmaxf(iwr, 0.0f) * fmaxf(ihr, 0.0f);
            const float uni = (parea + tarea) - inter;
            // enclosing box via identity: cw = pw + tw - iwr  (>= max(pw,tw) >= 0)
            const float cw = (pb.z + t.z) - iwr;
            const float ch = (pb.w + t.w) - ihr;
            const float carea = cw * ch;
            // giou = inter/uni - (carea-uni)/carea = [carea*(inter-uni)+uni^2]/(uni*carea)
            const float num  = carea * (inter - uni) + uni * uni;
            const float giou = num * __builtin_amdgcn_rcpf(uni * carea);
            const float ccls = crow[icl[k]];
            rv[k] = COST_BBOX * l1 + COST_CLS * ccls - COST_GIOU * giou;
        }
        *reinterpret_cast<float4*>(optr) = make_float4(rv[0], rv[1], rv[2], rv[3]);
        optr += NT;
    }
}

// ----------------------------- generic fallback -----------------------------
__global__ __launch_bounds__(THREADS) void matcher_kernel_g(
    const float* __restrict__ logits, const float* __restrict__ boxes,
    const int* __restrict__ tids, const float* __restrict__ tboxes,
    float* __restrict__ out, int BN, int NC, int NT)
{
    extern __shared__ float s_cls_g[];
    const int tid  = threadIdx.x;
    const int row0 = blockIdx.x * ROWS;
    const int nrows = (BN - row0 < ROWS) ? (BN - row0) : ROWS;

    for (int t = tid; t < nrows * NC; t += THREADS) {
        const int r = t / NC, c = t - r * NC;
        const float x  = logits[(size_t)(row0 + r) * NC + c];
        const float p  = 1.0f / (1.0f + expf(-x));
        const float om = 1.0f - p;
        const float neg = (1.0f - ALPHA_F) * p * p * (-logf(om + EPS_F));
        const float pos = ALPHA_F * om * om        * (-logf(p + EPS_F));
        s_cls_g[r * NC + c] = pos - neg;
    }
    __syncthreads();

    for (int r = 0; r < nrows; ++r) {
        const int row = row0 + r;
        const float4 pb = reinterpret_cast<const float4*>(boxes)[row];
        const float px0 = pb.x - 0.5f * pb.z, py0 = pb.y - 0.5f * pb.w;
        const float px1 = pb.x + 0.5f * pb.z, py1 = pb.y + 0.5f * pb.w;
        const float parea = pb.z * pb.w;
        for (int j = tid; j < NT; j += THREADS) {
            const float4 b = reinterpret_cast<const float4*>(tboxes)[j];
            const float bx0 = b.x - 0.5f * b.z, by0 = b.y - 0.5f * b.w;
            const float bx1 = b.x + 0.5f * b.z, by1 = b.y + 0.5f * b.w;
            const float l1 = fabsf(pb.x - b.x) + fabsf(pb.y - b.y)
                           + fabsf(pb.z - b.z) + fabsf(pb.w - b.w);
            const float iw = fmaxf(fminf(px1, bx1) - fmaxf(px0, bx0), 0.0f);
            const float ih = fmaxf(fminf(py1, by1) - fmaxf(py0, by0), 0.0f);
            const float inter = iw * ih;
            const float uni = parea + b.z * b.w - inter;
            const float iou = inter / uni;
            const float cw = fmaxf(px1, bx1) - fminf(px0, bx0);
            const float ch = fmaxf(py1, by1) - fminf(py0, by0);
            const float carea = cw * ch;
            const float giou = iou - (carea - uni) / carea;
            const float ccls = s_cls_g[r * NC + tids[j]];
            out[(size_t)row * NT + j] = COST_BBOX * l1 + COST_CLS * ccls - COST_GIOU * giou;
        }
        __syncthreads();
    }
}

extern "C" void kernel_launch(void* const* d_in, const int* in_sizes, int n_in,
                              void* d_out, int out_size, void* d_ws, size_t ws_size,
                              hipStream_t stream) {
    const float* logits = (const float*)d_in[0];
    const float* boxes  = (const float*)d_in[1];
    const int*   tids   = (const int*)d_in[2];
    const float* tboxes = (const float*)d_in[3];
    float* out = (float*)d_out;

    const int BN = in_sizes[1] / 4;       // 14400
    const int NC = in_sizes[0] / BN;      // 91
    const int NT = in_sizes[2];           // 960

    if (NC == 91 && NT == 960 && BN % ROWS == 0) {
        const int grid = BN / ROWS;       // 1800
        matcher_kernel_s<91, 960><<<grid, THREADS, 0, stream>>>(
            logits, boxes, tids, tboxes, out);
    } else {
        const int grid = (BN + ROWS - 1) / ROWS;
        const size_t shmem = (size_t)ROWS * NC * sizeof(float);
        matcher_kernel_g<<<grid, THREADS, shmem, stream>>>(
            logits, boxes, tids, tboxes, out, BN, NC, NT);
    }
}

// Round 5
// 23.817 us; speedup vs baseline: 2.2274x; 1.0334x over previous
//
#include <hip/hip_runtime.h>
#include <math.h>

// HungarianMatcher cost matrix:
//   C[i,j] = 5*L1(pred_box_i, tgt_box_j) + 2*(pos-neg focal at tgt class j) - 2*GIoU
// Shapes: pred_logits [BN,NC], pred_boxes [BN,4], tgt_ids [NT], tgt_bbox [NT,4]
// BN=16*900=14400, NC=91, NT=960. Output [BN,NT] fp32.

#define ALPHA_F   0.25f
#define COST_CLS  2.0f
#define COST_BBOX 5.0f
#define COST_GIOU 2.0f
#define EPS_F     1e-8f

constexpr int THREADS = 256;

// ---------------------------- specialized kernel ----------------------------
template<int NC, int NT, int ROWS>
__global__ __launch_bounds__(THREADS, 6) void matcher_kernel_s(
    const float* __restrict__ logits,   // [BN, NC]
    const float* __restrict__ boxes,    // [BN, 4] cxcywh
    const int*   __restrict__ tids,     // [NT]
    const float* __restrict__ tboxes,   // [NT, 4] cxcywh
    float*       __restrict__ out)      // [BN, NT]
{
    constexpr int CLS_STRIDE = 96;            // 91 -> 96 floats (384 B row)
    constexpr int JPT = 4;                    // contiguous targets per thread
    constexpr int NJT = NT / JPT;             // 240 active threads
    constexpr int NTAB = ROWS * NC;           // 364 table entries
    constexpr int LPT  = (NTAB + THREADS - 1) / THREADS;   // 2
    __shared__ float s_cls[ROWS * CLS_STRIDE];             // 1.5 KB

    const int tid  = threadIdx.x;
    const int row0 = blockIdx.x * ROWS;
    const bool active = tid < NJT;

    // ---- this thread's 4 targets: fully derived, row-invariant registers ----
    float tcx[JPT], tcy[JPT], tw[JPT], th[JPT];
    float tx0[JPT], tx1[JPT], ty0[JPT], ty1[JPT], tarea[JPT];
    const float* cp[JPT];   // LDS gather base = s_cls + class_id  (addr-free gathers)
    if (active) {
        const int4 tv = reinterpret_cast<const int4*>(tids)[tid];
        const int ic[JPT] = {tv.x, tv.y, tv.z, tv.w};
        #pragma unroll
        for (int k = 0; k < JPT; ++k) {
            const float4 b = reinterpret_cast<const float4*>(tboxes)[tid * JPT + k];
            tcx[k] = b.x; tcy[k] = b.y; tw[k] = b.z; th[k] = b.w;
            const float hw = 0.5f * b.z, hh = 0.5f * b.w;
            tx0[k] = b.x - hw;  tx1[k] = b.x + hw;
            ty0[k] = b.y - hh;  ty1[k] = b.y + hh;
            tarea[k] = b.z * b.w;
            cp[k] = s_cls + ic[k];
        }
    } else {
        #pragma unroll
        for (int k = 0; k < JPT; ++k) {
            tcx[k]=tcy[k]=tw[k]=th[k]=tx0[k]=tx1[k]=ty0[k]=ty1[k]=tarea[k]=0.f;
            cp[k] = s_cls;
        }
    }

    // ---- focal class tables for ROWS rows (one coalesced pass) ----
    const float* __restrict__ lg = logits + (size_t)row0 * NC;
    #pragma unroll
    for (int i = 0; i < LPT; ++i) {
        const int t = tid + i * THREADS;
        if (t < NTAB) {
            const float x  = lg[t];
            const float p  = 1.0f / (1.0f + __expf(-x));
            const float om = 1.0f - p;
            const float neg = (1.0f - ALPHA_F) * p * p * (-__logf(om + EPS_F));
            const float pos = ALPHA_F * om * om        * (-__logf(p  + EPS_F));
            const int r = t / NC, c = t - r * NC;
            s_cls[r * CLS_STRIDE + c] = pos - neg;
        }
    }
    __syncthreads();   // the only barrier

    if (!active) return;

    float* __restrict__ optr = out + (size_t)row0 * NT + tid * JPT;
    #pragma unroll
    for (int r = 0; r < ROWS; ++r) {
        // block-uniform pred box -> scalar regs
        const float4 pb = reinterpret_cast<const float4*>(boxes)[row0 + r];
        const float px0 = pb.x - 0.5f * pb.z, py0 = pb.y - 0.5f * pb.w;
        const float px1 = pb.x + 0.5f * pb.z, py1 = pb.y + 0.5f * pb.w;
        const float parea = pb.z * pb.w;

        float rv[JPT];
        #pragma unroll
        for (int k = 0; k < JPT; ++k) {
            // L1 in cxcywh space (abs folds into VOP3 src modifiers)
            const float l1 = (fabsf(pb.x - tcx[k]) + fabsf(pb.y - tcy[k]))
                           + (fabsf(pb.z - tw[k])  + fabsf(pb.w - th[k]));
            // raw intersection extents (feed enclosing box too)
            const float iwr = fminf(px1, tx1[k]) - fmaxf(px0, tx0[k]);
            const float ihr = fminf(py1, ty1[k]) - fmaxf(py0, ty0[k]);
            const float inter = fmaxf(iwr, 0.0f) * fmaxf(ihr, 0.0f);
            const float uni = (parea + tarea[k]) - inter;
            // enclosing box via identity: cw = pw + tw - iwr
            const float cw = (pb.z + tw[k]) - iwr;
            const float ch = (pb.w + th[k]) - ihr;
            const float carea = cw * ch;
            // giou = [carea*(inter-uni)+uni^2] / (uni*carea), one rcp
            const float num  = carea * (inter - uni) + uni * uni;
            const float giou = num * __builtin_amdgcn_rcpf(uni * carea);
            // class gather: ds_read with compile-time row offset, no addr math
            const float ccls = cp[k][r * CLS_STRIDE];
            rv[k] = (COST_BBOX * l1 + COST_CLS * ccls) - COST_GIOU * giou;
        }
        *reinterpret_cast<float4*>(optr) = make_float4(rv[0], rv[1], rv[2], rv[3]);
        optr += NT;
    }
}

// ----------------------------- generic fallback -----------------------------
constexpr int GROWS = 8;
__global__ __launch_bounds__(THREADS) void matcher_kernel_g(
    const float* __restrict__ logits, const float* __restrict__ boxes,
    const int* __restrict__ tids, const float* __restrict__ tboxes,
    float* __restrict__ out, int BN, int NC, int NT)
{
    extern __shared__ float s_cls_g[];
    const int tid  = threadIdx.x;
    const int row0 = blockIdx.x * GROWS;
    const int nrows = (BN - row0 < GROWS) ? (BN - row0) : GROWS;

    for (int t = tid; t < nrows * NC; t += THREADS) {
        const int r = t / NC, c = t - r * NC;
        const float x  = logits[(size_t)(row0 + r) * NC + c];
        const float p  = 1.0f / (1.0f + expf(-x));
        const float om = 1.0f - p;
        const float neg = (1.0f - ALPHA_F) * p * p * (-logf(om + EPS_F));
        const float pos = ALPHA_F * om * om        * (-logf(p + EPS_F));
        s_cls_g[r * NC + c] = pos - neg;
    }
    __syncthreads();

    for (int r = 0; r < nrows; ++r) {
        const int row = row0 + r;
        const float4 pb = reinterpret_cast<const float4*>(boxes)[row];
        const float px0 = pb.x - 0.5f * pb.z, py0 = pb.y - 0.5f * pb.w;
        const float px1 = pb.x + 0.5f * pb.z, py1 = pb.y + 0.5f * pb.w;
        const float parea = pb.z * pb.w;
        for (int j = tid; j < NT; j += THREADS) {
            const float4 b = reinterpret_cast<const float4*>(tboxes)[j];
            const float bx0 = b.x - 0.5f * b.z, by0 = b.y - 0.5f * b.w;
            const float bx1 = b.x + 0.5f * b.z, by1 = b.y + 0.5f * b.w;
            const float l1 = fabsf(pb.x - b.x) + fabsf(pb.y - b.y)
                           + fabsf(pb.z - b.z) + fabsf(pb.w - b.w);
            const float iw = fmaxf(fminf(px1, bx1) - fmaxf(px0, bx0), 0.0f);
            const float ih = fmaxf(fminf(py1, by1) - fmaxf(py0, by0), 0.0f);
            const float inter = iw * ih;
            const float uni = parea + b.z * b.w - inter;
            const float iou = inter / uni;
            const float cw = fmaxf(px1, bx1) - fminf(px0, bx0);
            const float ch = fmaxf(py1, by1) - fminf(py0, by0);
            const float carea = cw * ch;
            const float giou = iou - (carea - uni) / carea;
            const float ccls = s_cls_g[r * NC + tids[j]];
            out[(size_t)row * NT + j] = COST_BBOX * l1 + COST_CLS * ccls - COST_GIOU * giou;
        }
        __syncthreads();
    }
}

extern "C" void kernel_launch(void* const* d_in, const int* in_sizes, int n_in,
                              void* d_out, int out_size, void* d_ws, size_t ws_size,
                              hipStream_t stream) {
    const float* logits = (const float*)d_in[0];
    const float* boxes  = (const float*)d_in[1];
    const int*   tids   = (const int*)d_in[2];
    const float* tboxes = (const float*)d_in[3];
    float* out = (float*)d_out;

    const int BN = in_sizes[1] / 4;       // 14400
    const int NC = in_sizes[0] / BN;      // 91
    const int NT = in_sizes[2];           // 960

    constexpr int ROWS = 4;
    if (NC == 91 && NT == 960 && BN % ROWS == 0) {
        const int grid = BN / ROWS;       // 3600
        matcher_kernel_s<91, 960, ROWS><<<grid, THREADS, 0, stream>>>(
            logits, boxes, tids, tboxes, out);
    } else {
        const int grid = (BN + GROWS - 1) / GROWS;
        const size_t shmem = (size_t)GROWS * NC * sizeof(float);
        matcher_kernel_g<<<grid, THREADS, shmem, stream>>>(
            logits, boxes, tids, tboxes, out, BN, NC, NT);
    }
}